// Round 8
// baseline (527.169 us; speedup 1.0000x reference)
//
#include <hip/hip_runtime.h>
#include <math.h>

#define N_TOK 16384
#define DDIM  4096
#define NEXP  64
#define TM    64             // tokens per block (R8: 64, halves Wp bytes/token)
#define WINF  256            // f32 columns staged per row per step (1 KB/row)
#define NSTEP (DDIM / WINF)  // 16 steps
#define LSTR  68             // LDS logit row stride
#define TAU   1e-3f          // near-tie refine threshold

typedef __attribute__((ext_vector_type(8))) short bf16x8;
typedef __attribute__((ext_vector_type(4))) float f32x4;

// Split 8 consecutive fp32 into hi/lo bf16 (truncation split: x = hi + lo + eps).
__device__ __forceinline__ void split8(f32x4 v0, f32x4 v1, bf16x8& hi, bf16x8& lo) {
    float f[8];
    *(f32x4*)&f[0] = v0;  *(f32x4*)&f[4] = v1;
    #pragma unroll
    for (int i = 0; i < 8; ++i) {
        unsigned u  = __float_as_uint(f[i]);
        unsigned uh = u & 0xFFFF0000u;
        float    rf = f[i] - __uint_as_float(uh);
        hi[i] = (short)(u >> 16);
        lo[i] = (short)(__float_as_uint(rf) >> 16);
    }
}

// ---------------- W pre-pack: fragment-ordered bf16 hi/lo (1 MB in d_ws) -----
// Wp[((c*4+t)*2+p)*512 + lane*8 .. +7] = split of W[t*16+(lane&15)][c*32+(lane>>4)*8 + 0..7]
__global__ __launch_bounds__(256) void pack_w_kernel(
    const float* __restrict__ W, short* __restrict__ Wp)
{
    const int c    = blockIdx.x;          // K chunk of 32
    const int tid  = threadIdx.x;
    const int t    = tid >> 6;
    const int lane = tid & 63;
    const int r16  = lane & 15;
    const int koct = lane >> 4;
    const float* src = W + (size_t)(t * 16 + r16) * DDIM + c * 32 + koct * 8;
    f32x4 b0 = *(const f32x4*)src;
    f32x4 b1 = *(const f32x4*)(src + 4);
    bf16x8 hi, lo;
    split8(b0, b1, hi, lo);
    short* d = Wp + ((size_t)(c * 4 + t) * 2) * 512 + lane * 8;
    *(bf16x8*)d         = hi;
    *(bf16x8*)(d + 512) = lo;
}

// ---------------- main kernel: TM=64, K-split-8, reg-staged double buffer ----
// R8 experiment: per-CU vmem bytes cut from 3 MB (TM=32: x 1MB + Wp 2MB) to
// 2 MB (x 1MB + Wp 1MB) at constant burst size / barrier structure — testing
// the "per-CU vmem delivery ~5 B/cyc is the binding limit" hypothesis.
// Ring: 2 buffers x 64 KB; buffer = [row 0..63][1 KB window], bytes stored
// XOR-swizzled: LDS[r][b] = x[r][win + (b ^ ((r&7)<<4))].
__global__ __launch_bounds__(512, 2) void topk_gate_kernel(
    const float* __restrict__ x, const short* __restrict__ Wp,
    const float* __restrict__ W, float* __restrict__ out)
{
    __shared__ __align__(16) char sraw[143360];  // ring 128K; Lg[8][64][68]=139264; red 4K
    __shared__ int    top_i[TM * 2];
    __shared__ float  top_w[TM * 2];
    __shared__ int    nflag;
    __shared__ int    flist[TM];
    __shared__ double lgd[NEXP];
    __shared__ int    rbi[2];
    __shared__ float  rbw[2];

    const int tid  = threadIdx.x;
    const int lane = tid & 63;
    const int w    = tid >> 6;            // wave 0..7 (uniform role, K-chunk owner)
    const int block_tok = blockIdx.x * TM;
    const int phase = (blockIdx.x >> 3) & 15;   // K-window rotation (kept from R7)
    const int r16  = lane & 15;
    const int koct = lane >> 4;
    const int m    = (r16 & 7) << 4;      // read-side XOR
    const int o0   = w * 128 + koct * 32; // this wave's chunk offset in window

    // staging: wave w owns local rows w*8 .. w*8+7 (16384 B global row stride)
    const char* xrow = (const char*)x
                     + (size_t)(block_tok + w * 8) * (DDIM * 4) + lane * 16;
    char* const wbase = sraw + w * 8192;

    f32x4 rAv[8], rBv[8];                 // all indexing fully unrolled (rule #20)

#define LOADR(dst, S) do {                                                   \
    const char* _s = xrow + (size_t)(S) * 1024;                              \
    _Pragma("unroll")                                                        \
    for (int j = 0; j < 8; ++j)                                              \
        dst[j] = *(const f32x4*)(_s + j * 16384);                            \
} while (0)

#define WRITER(src, B) do {                                                  \
    char* _d = wbase + (B) * 65536;                                          \
    _Pragma("unroll")                                                        \
    for (int j = 0; j < 8; ++j)                                              \
        *(f32x4*)(_d + j * 1024 + ((lane * 16) ^ (j << 4))) = src[j];        \
} while (0)

    f32x4 acc[4][4];
    #pragma unroll
    for (int tt = 0; tt < 4; ++tt)
        #pragma unroll
        for (int t = 0; t < 4; ++t) acc[tt][t] = (f32x4){0.f, 0.f, 0.f, 0.f};

#define COMPUTE(B, S) do {                                                   \
    const char* _buf = sraw + (B) * 65536;                                   \
    const int _cg = (S) * 8 + w;                 /* global K chunk */        \
    bf16x8 ah[4], al[4];                                                     \
    _Pragma("unroll")                                                        \
    for (int tt = 0; tt < 4; ++tt) {                                         \
        const char* xb = _buf + ((tt * 16 + r16) << 10);                     \
        f32x4 a0 = *(const f32x4*)(xb + (o0 ^ m));                           \
        f32x4 a1 = *(const f32x4*)(xb + ((o0 + 16) ^ m));                    \
        split8(a0, a1, ah[tt], al[tt]);                                      \
    }                                                                        \
    _Pragma("unroll")                                                        \
    for (int t = 0; t < 4; ++t) {                                            \
        const short* wb = Wp + ((size_t)(_cg * 4 + t) * 2) * 512 + lane * 8; \
        bf16x8 bh = *(const bf16x8*)wb;                                      \
        bf16x8 bl = *(const bf16x8*)(wb + 512);                              \
        _Pragma("unroll")                                                    \
        for (int tt = 0; tt < 4; ++tt) {                                     \
            acc[tt][t] = __builtin_amdgcn_mfma_f32_16x16x32_bf16(ah[tt], bh, acc[tt][t], 0, 0, 0); \
            acc[tt][t] = __builtin_amdgcn_mfma_f32_16x16x32_bf16(ah[tt], bl, acc[tt][t], 0, 0, 0); \
            acc[tt][t] = __builtin_amdgcn_mfma_f32_16x16x32_bf16(al[tt], bh, acc[tt][t], 0, 0, 0); \
        }                                                                    \
    }                                                                        \
} while (0)

    // ---- 2-deep reg pipeline over 16 rotated windows, double-buffered LDS ----
    LOADR(rAv, (phase + 0) & 15);
    LOADR(rBv, (phase + 1) & 15);
    #pragma unroll 1
    for (int si = 0; si < NSTEP; si += 2) {
        WRITER(rAv, 0);
        __syncthreads();
        if (si + 2 < NSTEP) LOADR(rAv, (phase + si + 2) & 15);
        COMPUTE(0, (phase + si) & 15);
        __syncthreads();
        WRITER(rBv, 1);
        __syncthreads();
        if (si + 3 < NSTEP) LOADR(rBv, (phase + si + 3) & 15);
        COMPUTE(1, (phase + si + 1) & 15);
        __syncthreads();
    }
#undef LOADR
#undef WRITER
#undef COMPUTE

    // ---- epilogue: per-partition logits into LDS (ring dead) ----
    float* Lg = (float*)sraw;             // [8][64][LSTR]
    #pragma unroll
    for (int tt = 0; tt < 4; ++tt)
        #pragma unroll
        for (int t = 0; t < 4; ++t)
            #pragma unroll
            for (int r = 0; r < 4; ++r)
                Lg[(w * TM + tt * 16 + koct * 4 + r) * LSTR + t * 16 + r16] = acc[tt][t][r];
    if (tid == 0) nflag = 0;
    __syncthreads();

    // ---- combine 8 K-partitions: 2 x 512 threads x (1 token, 4 experts) ----
    // Safe: each (row<64, e4) slot is read (qq=0) only by the thread that
    // writes it, and iter0 writes rows 0..31 while iter1 reads rows 32..63.
    #pragma unroll
    for (int jj = 0; jj < 2; ++jj) {
        const int flat = tid + jj * 512;
        const int tok  = flat >> 4;
        const int e4   = (flat & 15) * 4;
        float4 s0 = *(float4*)&Lg[(0 * TM + tok) * LSTR + e4];
        #pragma unroll
        for (int qq = 1; qq < 8; ++qq) {
            float4 v = *(float4*)&Lg[(qq * TM + tok) * LSTR + e4];
            s0.x += v.x; s0.y += v.y; s0.z += v.z; s0.w += v.w;
        }
        *(float4*)&Lg[tok * LSTR + e4] = s0;
    }
    __syncthreads();

    // ---- top-3 scan + 2-way softmax + near-tie flagging ----
    if (tid < TM) {
        float m1 = -INFINITY, m2 = -INFINITY, m3 = -INFINITY;
        int i1 = 0, i2 = 0;
        for (int e = 0; e < NEXP; ++e) {
            float v = Lg[tid * LSTR + e];
            if (v > m1)      { m3 = m2; m2 = m1; i2 = i1; m1 = v; i1 = e; }
            else if (v > m2) { m3 = m2; m2 = v; i2 = e; }
            else if (v > m3) { m3 = v; }
        }
        float d  = expf(m2 - m1);
        float rn = 1.0f / (1.0f + d);
        top_i[tid * 2 + 0] = i1;  top_i[tid * 2 + 1] = i2;
        top_w[tid * 2 + 0] = rn;  top_w[tid * 2 + 1] = d * rn;
        float2* oi = (float2*)(out + (size_t)N_TOK * NEXP);
        oi[block_tok + tid] = make_float2((float)i1, (float)i2);
        if ((m1 - m2 < TAU) || (m2 - m3 < TAU)) {
            int pp = atomicAdd(&nflag, 1);
            flist[pp] = tid;
        }
    }
    __syncthreads();

    // ---- dense weight scatter: 64 tokens x 64 experts = 1024 float4 ----
    {
        float4* ow = (float4*)(out + (size_t)block_tok * NEXP);
        #pragma unroll
        for (int jj = 0; jj < 2; ++jj) {
            const int flat = tid + jj * 512;
            const int tok  = flat >> 4;
            const int e4   = (flat & 15) * 4;
            int a1 = top_i[tok * 2], a2 = top_i[tok * 2 + 1];
            float v1 = top_w[tok * 2], v2 = top_w[tok * 2 + 1];
            float4 v; float* vp = (float*)&v;
            #pragma unroll
            for (int q = 0; q < 4; ++q) {
                int e = e4 + q;
                vp[q] = (e == a1) ? v1 : ((e == a2) ? v2 : 0.0f);
            }
            ow[flat] = v;
        }
    }
    __syncthreads();

    // ---- in-block fp64 re-resolution of flagged tokens ----
    double* red = (double*)(sraw + 139264);  // past Lg
    const int fn = nflag;
    for (int f = 0; f < fn; ++f) {
        const int tok = block_tok + flist[f];
        {
            const int e = tid & 63, q = tid >> 6;   // q: 0..7
            const float* wr = W + (size_t)e * DDIM + q * (DDIM / 8);
            const float* xr = x + (size_t)tok * DDIM + q * (DDIM / 8);
            double pp = 0.0;
            for (int k = 0; k < DDIM / 8; k += 4) {
                float4 wv = *(const float4*)(wr + k);
                float4 xv = *(const float4*)(xr + k);
                pp += (double)xv.x * (double)wv.x;
                pp += (double)xv.y * (double)wv.y;
                pp += (double)xv.z * (double)wv.z;
                pp += (double)xv.w * (double)wv.w;
            }
            red[tid] = pp;
        }
        __syncthreads();
        if (tid < 64) {
            double s = 0.0;
            #pragma unroll
            for (int j = 0; j < 8; ++j) s += red[tid + 64 * j];
            lgd[tid] = s;
        }
        __syncthreads();

        if (tid == 0) {
            double m1 = -INFINITY, m2 = -INFINITY;
            int i1 = 0, i2 = 0;
            for (int ee = 0; ee < NEXP; ++ee) {
                double v = lgd[ee];
                if (v > m1)      { m2 = m1; i2 = i1; m1 = v; i1 = ee; }
                else if (v > m2) { m2 = v; i2 = ee; }
            }
            double d  = exp(m2 - m1);
            double rn = 1.0 / (1.0 + d);
            rbi[0] = i1; rbi[1] = i2;
            rbw[0] = (float)rn; rbw[1] = (float)(d * rn);
            float2* oi = (float2*)(out + (size_t)N_TOK * NEXP);
            oi[tok] = make_float2((float)i1, (float)i2);
        }
        __syncthreads();

        if (tid < 16) {
            float4 v = make_float4(0.f, 0.f, 0.f, 0.f);
            float* vp = (float*)&v;
            #pragma unroll
            for (int qq = 0; qq < 4; ++qq) {
                int ee = tid * 4 + qq;
                if (ee == rbi[0]) vp[qq] = rbw[0];
                else if (ee == rbi[1]) vp[qq] = rbw[1];
            }
            ((float4*)(out + (size_t)tok * NEXP))[tid] = v;
        }
        __syncthreads();
    }
}

extern "C" void kernel_launch(void* const* d_in, const int* in_sizes, int n_in,
                              void* d_out, int out_size, void* d_ws, size_t ws_size,
                              hipStream_t stream) {
    const float* x = (const float*)d_in[0];   // [16384, 4096] fp32
    const float* W = (const float*)d_in[1];   // [64, 4096] fp32
    float* out = (float*)d_out;               // weights [16384*64] then indices [16384*2]
    short* Wp  = (short*)d_ws;                // 1 MB packed W (bf16 hi/lo fragments)
    (void)in_sizes; (void)n_in; (void)ws_size; (void)out_size;

    hipLaunchKernelGGL(pack_w_kernel, dim3(DDIM / 32), dim3(256), 0, stream, W, Wp);
    hipLaunchKernelGGL(topk_gate_kernel, dim3(N_TOK / TM), dim3(512), 0, stream,
                       x, Wp, W, out);
}

// Round 9
// 514.051 us; speedup vs baseline: 1.0255x; 1.0255x over previous
//
#include <hip/hip_runtime.h>
#include <math.h>

#define N_TOK 16384
#define DDIM  4096
#define NEXP  64
#define TM    64             // tokens per block
#define NW    16             // waves per block (16 waves/CU — concurrency floor)
#define WINF  256            // f32 columns staged per row per step (1 KB/row)
#define NSTEP (DDIM / WINF)  // 16 windows
#define LSTR  68             // LDS logit row stride
#define TAU   1e-3f          // near-tie refine threshold

typedef __attribute__((ext_vector_type(8))) short bf16x8;
typedef __attribute__((ext_vector_type(4))) float f32x4;

// Split 8 consecutive fp32 into hi/lo bf16 (truncation split: x = hi + lo + eps).
__device__ __forceinline__ void split8(f32x4 v0, f32x4 v1, bf16x8& hi, bf16x8& lo) {
    float f[8];
    *(f32x4*)&f[0] = v0;  *(f32x4*)&f[4] = v1;
    #pragma unroll
    for (int i = 0; i < 8; ++i) {
        unsigned u  = __float_as_uint(f[i]);
        unsigned uh = u & 0xFFFF0000u;
        float    rf = f[i] - __uint_as_float(uh);
        hi[i] = (short)(u >> 16);
        lo[i] = (short)(__float_as_uint(rf) >> 16);
    }
}

// ---------------- W pre-pack: fragment-ordered bf16 hi/lo (1 MB in d_ws) -----
// Wp[((c*4+t)*2+p)*512 + lane*8 .. +7] = split of W[t*16+(lane&15)][c*32+(lane>>4)*8 + 0..7]
__global__ __launch_bounds__(256) void pack_w_kernel(
    const float* __restrict__ W, short* __restrict__ Wp)
{
    const int c    = blockIdx.x;          // K chunk of 32
    const int tid  = threadIdx.x;
    const int t    = tid >> 6;
    const int lane = tid & 63;
    const int r16  = lane & 15;
    const int koct = lane >> 4;
    const float* src = W + (size_t)(t * 16 + r16) * DDIM + c * 32 + koct * 8;
    f32x4 b0 = *(const f32x4*)src;
    f32x4 b1 = *(const f32x4*)(src + 4);
    bf16x8 hi, lo;
    split8(b0, b1, hi, lo);
    short* d = Wp + ((size_t)(c * 4 + t) * 2) * 512 + lane * 8;
    *(bf16x8*)d         = hi;
    *(bf16x8*)(d + 512) = lo;
}

// ---------------- main kernel: TM=64, 16 waves, Wp read once per block -------
// R9: fixes R8's concurrency deficit (8->16 issuing waves/CU) while keeping
// R8's byte reduction (512 MB total request traffic). Wave w owns K-chunk
// (w&7) of every window for expert-half (w>>3): each Wp chunk is read exactly
// once per block. acc[4][2] keeps VGPR < 128 (required for 16 waves/CU).
// Ring: 2 x 64 KB; buffer = [row 0..63][1 KB window], XOR-swizzled
// LDS[r][b] = x[r][win + (b ^ ((r&7)<<4))].
__global__ __launch_bounds__(1024, 4) void topk_gate_kernel(
    const float* __restrict__ x, const short* __restrict__ Wp,
    const float* __restrict__ W, float* __restrict__ out)
{
    __shared__ __align__(16) char sraw[147456]; // ring 2x64K=131072; Lg 139264 + red 8192
    __shared__ int    top_i[TM * 2];
    __shared__ float  top_w[TM * 2];
    __shared__ int    nflag;
    __shared__ int    flist[TM];
    __shared__ double lgd[NEXP];
    __shared__ int    rbi[2];
    __shared__ float  rbw[2];

    const int tid  = threadIdx.x;
    const int lane = tid & 63;
    const int w    = tid >> 6;            // wave 0..15
    const int cj   = w & 7;               // K-chunk-in-window owned by this wave
    const int th   = w >> 3;              // expert half (0: e<32, 1: e>=32)
    const int block_tok = blockIdx.x * TM;
    const int phase = (blockIdx.x >> 3) & 15;   // K-window rotation (kept from R7)
    const int r16  = lane & 15;
    const int koct = lane >> 4;
    const int m    = (r16 & 7) << 4;      // read-side XOR
    const int o0   = cj * 128 + koct * 32;

    // staging: wave w owns local rows w*4 .. w*4+3 (16384 B global row stride)
    const char* xrow = (const char*)x
                     + (size_t)(block_tok + w * 4) * (DDIM * 4) + lane * 16;
    const int sw0 = (lane * 16) ^ ((((w * 4) + 0) & 7) << 4);
    const int sw1 = (lane * 16) ^ ((((w * 4) + 1) & 7) << 4);
    const int sw2 = (lane * 16) ^ ((((w * 4) + 2) & 7) << 4);
    const int sw3 = (lane * 16) ^ ((((w * 4) + 3) & 7) << 4);
    char* const wbase = sraw + (w * 4) * 1024;

    f32x4 r0, r1, r2, r3;                 // single staging reg set (2-phase T3)

#define LOADR(S) do {                                                        \
    const char* _s = xrow + (size_t)(S) * 1024;                              \
    r0 = *(const f32x4*)(_s);                                                \
    r1 = *(const f32x4*)(_s + 16384);                                        \
    r2 = *(const f32x4*)(_s + 32768);                                        \
    r3 = *(const f32x4*)(_s + 49152);                                        \
} while (0)

#define WRITER(B) do {                                                       \
    char* _d = wbase + (B) * 65536;                                          \
    *(f32x4*)(_d +        sw0) = r0;                                         \
    *(f32x4*)(_d + 1024 + sw1) = r1;                                         \
    *(f32x4*)(_d + 2048 + sw2) = r2;                                         \
    *(f32x4*)(_d + 3072 + sw3) = r3;                                         \
} while (0)

    f32x4 acc[4][2];                      // [token-tile][expert-tile of half]
    #pragma unroll
    for (int tt = 0; tt < 4; ++tt)
        #pragma unroll
        for (int t = 0; t < 2; ++t) acc[tt][t] = (f32x4){0.f, 0.f, 0.f, 0.f};

#define COMPUTE(B, S) do {                                                   \
    const char* _buf = sraw + (B) * 65536;                                   \
    const int _cg = (S) * 8 + cj;                /* global K chunk */        \
    bf16x8 ah[4], al[4];                                                     \
    _Pragma("unroll")                                                        \
    for (int tt = 0; tt < 4; ++tt) {                                         \
        const char* xb = _buf + ((tt * 16 + r16) << 10);                     \
        f32x4 a0 = *(const f32x4*)(xb + (o0 ^ m));                           \
        f32x4 a1 = *(const f32x4*)(xb + ((o0 + 16) ^ m));                    \
        split8(a0, a1, ah[tt], al[tt]);                                      \
    }                                                                        \
    _Pragma("unroll")                                                        \
    for (int t = 0; t < 2; ++t) {                                            \
        const int T = th * 2 + t;                                            \
        const short* wb = Wp + ((size_t)(_cg * 4 + T) * 2) * 512 + lane * 8; \
        bf16x8 bh = *(const bf16x8*)wb;                                      \
        bf16x8 bl = *(const bf16x8*)(wb + 512);                              \
        _Pragma("unroll")                                                    \
        for (int tt = 0; tt < 4; ++tt) {                                     \
            acc[tt][t] = __builtin_amdgcn_mfma_f32_16x16x32_bf16(ah[tt], bh, acc[tt][t], 0, 0, 0); \
            acc[tt][t] = __builtin_amdgcn_mfma_f32_16x16x32_bf16(ah[tt], bl, acc[tt][t], 0, 0, 0); \
            acc[tt][t] = __builtin_amdgcn_mfma_f32_16x16x32_bf16(al[tt], bh, acc[tt][t], 0, 0, 0); \
        }                                                                    \
    }                                                                        \
} while (0)

    // ---- 2-phase pipeline over 16 rotated windows, double-buffered LDS ----
    LOADR((phase + 0) & 15);
    #pragma unroll 1
    for (int si = 0; si < NSTEP; ++si) {
        WRITER(si & 1);                    // waits the loads issued last iter
        __syncthreads();
        if (si + 1 < NSTEP) LOADR((phase + si + 1) & 15);
        COMPUTE(si & 1, (phase + si) & 15);
        __syncthreads();
    }
#undef LOADR
#undef WRITER
#undef COMPUTE

    // ---- epilogue: partial logits into LDS (ring dead) ----
    // Lg[partial j = cj][token 0..63][expert 0..63 (+pad)]; wave (j, th) writes
    // its expert half of partial j.
    float* Lg = (float*)sraw;             // [8][64][LSTR]
    #pragma unroll
    for (int tt = 0; tt < 4; ++tt)
        #pragma unroll
        for (int t = 0; t < 2; ++t)
            #pragma unroll
            for (int r = 0; r < 4; ++r)
                Lg[(cj * TM + tt * 16 + koct * 4 + r) * LSTR
                   + th * 32 + t * 16 + r16] = acc[tt][t][r];
    if (tid == 0) nflag = 0;
    __syncthreads();

    // ---- combine 8 K-partials: 1024 threads x (1 token, 4 experts) ----
    {
        const int tok = tid >> 4;
        const int e4  = (tid & 15) * 4;
        float4 s0 = *(float4*)&Lg[(0 * TM + tok) * LSTR + e4];
        #pragma unroll
        for (int qq = 1; qq < 8; ++qq) {
            float4 v = *(float4*)&Lg[(qq * TM + tok) * LSTR + e4];
            s0.x += v.x; s0.y += v.y; s0.z += v.z; s0.w += v.w;
        }
        *(float4*)&Lg[tok * LSTR + e4] = s0;
    }
    __syncthreads();

    // ---- top-3 scan + 2-way softmax + near-tie flagging ----
    if (tid < TM) {
        float m1 = -INFINITY, m2 = -INFINITY, m3 = -INFINITY;
        int i1 = 0, i2 = 0;
        for (int e = 0; e < NEXP; ++e) {
            float v = Lg[tid * LSTR + e];
            if (v > m1)      { m3 = m2; m2 = m1; i2 = i1; m1 = v; i1 = e; }
            else if (v > m2) { m3 = m2; m2 = v; i2 = e; }
            else if (v > m3) { m3 = v; }
        }
        float d  = expf(m2 - m1);
        float rn = 1.0f / (1.0f + d);
        top_i[tid * 2 + 0] = i1;  top_i[tid * 2 + 1] = i2;
        top_w[tid * 2 + 0] = rn;  top_w[tid * 2 + 1] = d * rn;
        float2* oi = (float2*)(out + (size_t)N_TOK * NEXP);
        oi[block_tok + tid] = make_float2((float)i1, (float)i2);
        if ((m1 - m2 < TAU) || (m2 - m3 < TAU)) {
            int pp = atomicAdd(&nflag, 1);
            flist[pp] = tid;
        }
    }
    __syncthreads();

    // ---- dense weight scatter: 64 tokens x 64 experts = 1024 float4 ----
    {
        float4* ow = (float4*)(out + (size_t)block_tok * NEXP);
        const int tok = tid >> 4;
        const int e4  = (tid & 15) * 4;
        int a1 = top_i[tok * 2], a2 = top_i[tok * 2 + 1];
        float v1 = top_w[tok * 2], v2 = top_w[tok * 2 + 1];
        float4 v; float* vp = (float*)&v;
        #pragma unroll
        for (int q = 0; q < 4; ++q) {
            int e = e4 + q;
            vp[q] = (e == a1) ? v1 : ((e == a2) ? v2 : 0.0f);
        }
        ow[tid] = v;
    }
    __syncthreads();

    // ---- in-block fp64 re-resolution of flagged tokens ----
    double* red = (double*)(sraw + 139264);  // past Lg
    const int fn = nflag;
    for (int f = 0; f < fn; ++f) {
        const int tok = block_tok + flist[f];
        {
            const int e = tid & 63, q = tid >> 6;   // q: 0..15
            const float* wr = W + (size_t)e * DDIM + q * (DDIM / 16);
            const float* xr = x + (size_t)tok * DDIM + q * (DDIM / 16);
            double pp = 0.0;
            for (int k = 0; k < DDIM / 16; k += 4) {
                float4 wv = *(const float4*)(wr + k);
                float4 xv = *(const float4*)(xr + k);
                pp += (double)xv.x * (double)wv.x;
                pp += (double)xv.y * (double)wv.y;
                pp += (double)xv.z * (double)wv.z;
                pp += (double)xv.w * (double)wv.w;
            }
            red[tid] = pp;
        }
        __syncthreads();
        if (tid < 64) {
            double s = 0.0;
            #pragma unroll
            for (int j = 0; j < 16; ++j) s += red[tid + 64 * j];
            lgd[tid] = s;
        }
        __syncthreads();

        if (tid == 0) {
            double m1 = -INFINITY, m2 = -INFINITY;
            int i1 = 0, i2 = 0;
            for (int ee = 0; ee < NEXP; ++ee) {
                double v = lgd[ee];
                if (v > m1)      { m2 = m1; i2 = i1; m1 = v; i1 = ee; }
                else if (v > m2) { m2 = v; i2 = ee; }
            }
            double d  = exp(m2 - m1);
            double rn = 1.0 / (1.0 + d);
            rbi[0] = i1; rbi[1] = i2;
            rbw[0] = (float)rn; rbw[1] = (float)(d * rn);
            float2* oi = (float2*)(out + (size_t)N_TOK * NEXP);
            oi[tok] = make_float2((float)i1, (float)i2);
        }
        __syncthreads();

        if (tid < 16) {
            float4 v = make_float4(0.f, 0.f, 0.f, 0.f);
            float* vp = (float*)&v;
            #pragma unroll
            for (int qq = 0; qq < 4; ++qq) {
                int ee = tid * 4 + qq;
                if (ee == rbi[0]) vp[qq] = rbw[0];
                else if (ee == rbi[1]) vp[qq] = rbw[1];
            }
            ((float4*)(out + (size_t)tok * NEXP))[tid] = v;
        }
        __syncthreads();
    }
}

extern "C" void kernel_launch(void* const* d_in, const int* in_sizes, int n_in,
                              void* d_out, int out_size, void* d_ws, size_t ws_size,
                              hipStream_t stream) {
    const float* x = (const float*)d_in[0];   // [16384, 4096] fp32
    const float* W = (const float*)d_in[1];   // [64, 4096] fp32
    float* out = (float*)d_out;               // weights [16384*64] then indices [16384*2]
    short* Wp  = (short*)d_ws;                // 1 MB packed W (bf16 hi/lo fragments)
    (void)in_sizes; (void)n_in; (void)ws_size; (void)out_size;

    hipLaunchKernelGGL(pack_w_kernel, dim3(DDIM / 32), dim3(256), 0, stream, W, Wp);
    hipLaunchKernelGGL(topk_gate_kernel, dim3(N_TOK / TM), dim3(1024), 0, stream,
                       x, Wp, W, out);
}

// Round 10
// 475.438 us; speedup vs baseline: 1.1088x; 1.0812x over previous
//
#include <hip/hip_runtime.h>
#include <math.h>

#define N_TOK 16384
#define DDIM  4096
#define NEXP  64
#define TM    32             // tokens per block
#define WINF  256            // f32 columns staged per row per step (1 KB/row)
#define NSTEP (DDIM / WINF)  // 16 windows
#define LSTR  68             // LDS logit row stride
#define TAU   1e-3f          // near-tie refine threshold

typedef __attribute__((ext_vector_type(8))) short bf16x8;
typedef __attribute__((ext_vector_type(4))) float f32x4;

// Split 8 consecutive fp32 into hi/lo bf16 (truncation split: x = hi + lo + eps).
__device__ __forceinline__ void split8(f32x4 v0, f32x4 v1, bf16x8& hi, bf16x8& lo) {
    float f[8];
    *(f32x4*)&f[0] = v0;  *(f32x4*)&f[4] = v1;
    #pragma unroll
    for (int i = 0; i < 8; ++i) {
        unsigned u  = __float_as_uint(f[i]);
        unsigned uh = u & 0xFFFF0000u;
        float    rf = f[i] - __uint_as_float(uh);
        hi[i] = (short)(u >> 16);
        lo[i] = (short)(__float_as_uint(rf) >> 16);
    }
}

// ---------------- W pre-pack: fragment-ordered bf16 hi/lo (1 MB in d_ws) -----
// Wp[((c*4+t)*2+p)*512 + lane*8 .. +7] = split of W[t*16+(lane&15)][c*32+(lane>>4)*8 + 0..7]
__global__ __launch_bounds__(256) void pack_w_kernel(
    const float* __restrict__ W, short* __restrict__ Wp)
{
    const int c    = blockIdx.x;          // K chunk of 32
    const int tid  = threadIdx.x;
    const int t    = tid >> 6;
    const int lane = tid & 63;
    const int r16  = lane & 15;
    const int koct = lane >> 4;
    const float* src = W + (size_t)(t * 16 + r16) * DDIM + c * 32 + koct * 8;
    f32x4 b0 = *(const f32x4*)src;
    f32x4 b1 = *(const f32x4*)(src + 4);
    bf16x8 hi, lo;
    split8(b0, b1, hi, lo);
    short* d = Wp + ((size_t)(c * 4 + t) * 2) * 512 + lane * 8;
    *(bf16x8*)d         = hi;
    *(bf16x8*)(d + 512) = lo;
}

// ---------------- main kernel: 4-deep plain-load pipeline, raw barriers ------
// R10 tests the last untested quadrant: PLAIN global loads x SUSTAINED deep
// in-flight window. Four named reg-sets hold windows s+1..s+4 in flight
// (~16 KB/wave); the per-step barrier is a raw s_barrier preceded only by
// lgkmcnt(0) — vmcnt is NEVER drained in the loop (compiler inserts counted
// dep-waits before each ds_write of a loaded set).
// Ring: 4 slots x 32 KB; slot = [row 0..31][1 KB window], XOR-swizzled
// LDS[r][b] = x[r][win + (b ^ ((r&7)<<4))].
// Ring-reuse safety: slot k written at step s (pre-barrier s), last read at
// step s-4 (post-barrier s-4, pre-barrier s-3) -> >=3 barriers apart.
__global__ __launch_bounds__(512, 2) void topk_gate_kernel(
    const float* __restrict__ x, const short* __restrict__ Wp,
    const float* __restrict__ W, float* __restrict__ out)
{
    __shared__ __align__(16) char sraw[131072];  // ring 4x32K; Lg+red alias
    __shared__ int    top_i[TM * 2];
    __shared__ float  top_w[TM * 2];
    __shared__ int    nflag;
    __shared__ int    flist[TM];
    __shared__ double lgd[NEXP];
    __shared__ int    rbi[2];
    __shared__ float  rbw[2];

    const int tid  = threadIdx.x;
    const int lane = tid & 63;
    const int w    = tid >> 6;            // wave 0..7 (uniform role)
    const int block_tok = blockIdx.x * TM;
    const int phase = (blockIdx.x >> 3) & 15;   // K-window rotation (kept)
    const int r16  = lane & 15;
    const int koct = lane >> 4;
    const int m    = (r16 & 7) << 4;      // read-side XOR
    const int o0   = w * 128 + koct * 32; // this wave's chunk offset in window

    // staging: wave w owns local rows w*4 .. w*4+3 (16384 B global row stride)
    const char* xrow = (const char*)x
                     + (size_t)(block_tok + w * 4) * (DDIM * 4) + lane * 16;
    const int sw0 = (lane * 16) ^ ((((w * 4) + 0) & 7) << 4);
    const int sw1 = (lane * 16) ^ ((((w * 4) + 1) & 7) << 4);
    const int sw2 = (lane * 16) ^ ((((w * 4) + 2) & 7) << 4);
    const int sw3 = (lane * 16) ^ ((((w * 4) + 3) & 7) << 4);

    // 4 named staging reg-sets (static indexing only — rule #20)
    f32x4 pA0, pA1, pA2, pA3, pB0, pB1, pB2, pB3;
    f32x4 pC0, pC1, pC2, pC3, pD0, pD1, pD2, pD3;

#define LOADR(a0, a1, a2, a3, S) do {                                        \
    const char* _s = xrow + (size_t)(S) * 1024;                              \
    a0 = *(const f32x4*)(_s);                                                \
    a1 = *(const f32x4*)(_s + 16384);                                        \
    a2 = *(const f32x4*)(_s + 32768);                                        \
    a3 = *(const f32x4*)(_s + 49152);                                        \
} while (0)

#define WRITER(a0, a1, a2, a3, SLOT) do {                                    \
    char* _d = sraw + (SLOT) * 32768 + (w * 4) * 1024;                       \
    *(f32x4*)(_d +        sw0) = a0;                                         \
    *(f32x4*)(_d + 1024 + sw1) = a1;                                         \
    *(f32x4*)(_d + 2048 + sw2) = a2;                                         \
    *(f32x4*)(_d + 3072 + sw3) = a3;                                         \
} while (0)

    f32x4 acc[2][4];
    #pragma unroll
    for (int tt = 0; tt < 2; ++tt)
        #pragma unroll
        for (int t = 0; t < 4; ++t) acc[tt][t] = (f32x4){0.f, 0.f, 0.f, 0.f};

#define COMPUTE(SLOT, SWIN) do {                                             \
    const char* _buf = sraw + (SLOT) * 32768;                                \
    const int _cg = (SWIN) * 8 + w;              /* global K chunk */        \
    bf16x8 ah[2], al[2];                                                     \
    _Pragma("unroll")                                                        \
    for (int tt = 0; tt < 2; ++tt) {                                         \
        const char* xb = _buf + ((tt * 16 + r16) << 10);                     \
        f32x4 a0 = *(const f32x4*)(xb + (o0 ^ m));                           \
        f32x4 a1 = *(const f32x4*)(xb + ((o0 + 16) ^ m));                    \
        split8(a0, a1, ah[tt], al[tt]);                                      \
    }                                                                        \
    _Pragma("unroll")                                                        \
    for (int t = 0; t < 4; ++t) {                                            \
        const short* wb = Wp + ((size_t)(_cg * 4 + t) * 2) * 512 + lane * 8; \
        bf16x8 bh = *(const bf16x8*)wb;                                      \
        bf16x8 bl = *(const bf16x8*)(wb + 512);                              \
        _Pragma("unroll")                                                    \
        for (int tt = 0; tt < 2; ++tt) {                                     \
            acc[tt][t] = __builtin_amdgcn_mfma_f32_16x16x32_bf16(ah[tt], bh, acc[tt][t], 0, 0, 0); \
            acc[tt][t] = __builtin_amdgcn_mfma_f32_16x16x32_bf16(ah[tt], bl, acc[tt][t], 0, 0, 0); \
            acc[tt][t] = __builtin_amdgcn_mfma_f32_16x16x32_bf16(al[tt], bh, acc[tt][t], 0, 0, 0); \
        }                                                                    \
    }                                                                        \
} while (0)

    // One step: write landed set -> barrier (NO vmcnt drain) -> refill -> compute.
#define STEP(S, a0, a1, a2, a3) do {                                         \
    WRITER(a0, a1, a2, a3, (S) & 3);   /* compiler: counted vmcnt dep-wait */\
    asm volatile("s_waitcnt lgkmcnt(0)" ::: "memory");                       \
    __builtin_amdgcn_sched_barrier(0);                                       \
    __builtin_amdgcn_s_barrier();                                            \
    __builtin_amdgcn_sched_barrier(0);                                       \
    if ((S) + 4 < NSTEP) LOADR(a0, a1, a2, a3, (phase + (S) + 4) & 15);      \
    __builtin_amdgcn_sched_barrier(0);                                       \
    COMPUTE((S) & 3, (phase + (S)) & 15);                                    \
} while (0)

    // ---- prologue: 4 windows in flight before the first barrier ----
    LOADR(pA0, pA1, pA2, pA3, (phase + 0) & 15);
    LOADR(pB0, pB1, pB2, pB3, (phase + 1) & 15);
    LOADR(pC0, pC1, pC2, pC3, (phase + 2) & 15);
    LOADR(pD0, pD1, pD2, pD3, (phase + 3) & 15);
    #pragma unroll
    for (int sb = 0; sb < NSTEP; sb += 4) {
        STEP(sb + 0, pA0, pA1, pA2, pA3);
        STEP(sb + 1, pB0, pB1, pB2, pB3);
        STEP(sb + 2, pC0, pC1, pC2, pC3);
        STEP(sb + 3, pD0, pD1, pD2, pD3);
    }
#undef LOADR
#undef WRITER
#undef COMPUTE
#undef STEP

    // ---- epilogue: per-partition logits into LDS ----
    // Safe vs in-flight COMPUTE(15): that reads only slot 3 (bytes 98304+),
    // Lg occupies bytes [0, 69632) = slots 0-2.
    float* Lg = (float*)sraw;             // [8][32][LSTR]
    #pragma unroll
    for (int tt = 0; tt < 2; ++tt)
        #pragma unroll
        for (int t = 0; t < 4; ++t)
            #pragma unroll
            for (int r = 0; r < 4; ++r)
                Lg[(w * TM + tt * 16 + koct * 4 + r) * LSTR + t * 16 + r16] = acc[tt][t][r];
    if (tid == 0) nflag = 0;
    __syncthreads();

    // ---- combine 8 K-partitions: 512 threads x (1 token, 4 experts) ----
    {
        const int tok = tid >> 4;
        const int e4  = (tid & 15) * 4;
        float4 s0 = *(float4*)&Lg[(0 * TM + tok) * LSTR + e4];
        #pragma unroll
        for (int qq = 1; qq < 8; ++qq) {
            float4 v = *(float4*)&Lg[(qq * TM + tok) * LSTR + e4];
            s0.x += v.x; s0.y += v.y; s0.z += v.z; s0.w += v.w;
        }
        *(float4*)&Lg[tok * LSTR + e4] = s0;
    }
    __syncthreads();

    // ---- top-3 scan + 2-way softmax + near-tie flagging ----
    if (tid < TM) {
        float m1 = -INFINITY, m2 = -INFINITY, m3 = -INFINITY;
        int i1 = 0, i2 = 0;
        for (int e = 0; e < NEXP; ++e) {
            float v = Lg[tid * LSTR + e];
            if (v > m1)      { m3 = m2; m2 = m1; i2 = i1; m1 = v; i1 = e; }
            else if (v > m2) { m3 = m2; m2 = v; i2 = e; }
            else if (v > m3) { m3 = v; }
        }
        float d  = expf(m2 - m1);
        float rn = 1.0f / (1.0f + d);
        top_i[tid * 2 + 0] = i1;  top_i[tid * 2 + 1] = i2;
        top_w[tid * 2 + 0] = rn;  top_w[tid * 2 + 1] = d * rn;
        float2* oi = (float2*)(out + (size_t)N_TOK * NEXP);
        oi[block_tok + tid] = make_float2((float)i1, (float)i2);
        if ((m1 - m2 < TAU) || (m2 - m3 < TAU)) {
            int pp = atomicAdd(&nflag, 1);
            flist[pp] = tid;
        }
    }
    __syncthreads();

    // ---- dense weight scatter: 32 tokens x 64 experts = 512 float4 ----
    {
        float4* ow = (float4*)(out + (size_t)block_tok * NEXP);
        const int tok = tid >> 4;
        const int e4  = (tid & 15) * 4;
        int a1 = top_i[tok * 2], a2 = top_i[tok * 2 + 1];
        float v1 = top_w[tok * 2], v2 = top_w[tok * 2 + 1];
        float4 v; float* vp = (float*)&v;
        #pragma unroll
        for (int q = 0; q < 4; ++q) {
            int e = e4 + q;
            vp[q] = (e == a1) ? v1 : ((e == a2) ? v2 : 0.0f);
        }
        ow[tid] = v;
    }
    __syncthreads();

    // ---- in-block fp64 re-resolution of flagged tokens ----
    double* red = (double*)(sraw + 69632);   // past Lg, inside sraw
    const int fn = nflag;
    for (int f = 0; f < fn; ++f) {
        const int tok = block_tok + flist[f];
        {
            const int e = tid & 63, q = tid >> 6;   // q: 0..7
            const float* wr = W + (size_t)e * DDIM + q * (DDIM / 8);
            const float* xr = x + (size_t)tok * DDIM + q * (DDIM / 8);
            double pp = 0.0;
            for (int k = 0; k < DDIM / 8; k += 4) {
                float4 wv = *(const float4*)(wr + k);
                float4 xv = *(const float4*)(xr + k);
                pp += (double)xv.x * (double)wv.x;
                pp += (double)xv.y * (double)wv.y;
                pp += (double)xv.z * (double)wv.z;
                pp += (double)xv.w * (double)wv.w;
            }
            red[tid] = pp;
        }
        __syncthreads();
        if (tid < 64) {
            double s = 0.0;
            #pragma unroll
            for (int j = 0; j < 8; ++j) s += red[tid + 64 * j];
            lgd[tid] = s;
        }
        __syncthreads();

        if (tid == 0) {
            double m1 = -INFINITY, m2 = -INFINITY;
            int i1 = 0, i2 = 0;
            for (int ee = 0; ee < NEXP; ++ee) {
                double v = lgd[ee];
                if (v > m1)      { m2 = m1; i2 = i1; m1 = v; i1 = ee; }
                else if (v > m2) { m2 = v; i2 = ee; }
            }
            double d  = exp(m2 - m1);
            double rn = 1.0 / (1.0 + d);
            rbi[0] = i1; rbi[1] = i2;
            rbw[0] = (float)rn; rbw[1] = (float)(d * rn);
            float2* oi = (float2*)(out + (size_t)N_TOK * NEXP);
            oi[tok] = make_float2((float)i1, (float)i2);
        }
        __syncthreads();

        if (tid < 16) {
            float4 v = make_float4(0.f, 0.f, 0.f, 0.f);
            float* vp = (float*)&v;
            #pragma unroll
            for (int qq = 0; qq < 4; ++qq) {
                int ee = tid * 4 + qq;
                if (ee == rbi[0]) vp[qq] = rbw[0];
                else if (ee == rbi[1]) vp[qq] = rbw[1];
            }
            ((float4*)(out + (size_t)tok * NEXP))[tid] = v;
        }
        __syncthreads();
    }
}

extern "C" void kernel_launch(void* const* d_in, const int* in_sizes, int n_in,
                              void* d_out, int out_size, void* d_ws, size_t ws_size,
                              hipStream_t stream) {
    const float* x = (const float*)d_in[0];   // [16384, 4096] fp32
    const float* W = (const float*)d_in[1];   // [64, 4096] fp32
    float* out = (float*)d_out;               // weights [16384*64] then indices [16384*2]
    short* Wp  = (short*)d_ws;                // 1 MB packed W (bf16 hi/lo fragments)
    (void)in_sizes; (void)n_in; (void)ws_size; (void)out_size;

    hipLaunchKernelGGL(pack_w_kernel, dim3(DDIM / 32), dim3(256), 0, stream, W, Wp);
    hipLaunchKernelGGL(topk_gate_kernel, dim3(N_TOK / TM), dim3(512), 0, stream,
                       x, Wp, W, out);
}